// Round 1
// baseline (256.145 us; speedup 1.0000x reference)
//
#include <hip/hip_runtime.h>
#include <hip/hip_bf16.h>

typedef __attribute__((ext_vector_type(8))) short bf16x8;
typedef __attribute__((ext_vector_type(4))) float f32x4;
typedef __attribute__((ext_vector_type(4))) unsigned int u32x4;

#define NB 2048

static __device__ __forceinline__ unsigned short f2bf(float f) {
  unsigned int u = __builtin_bit_cast(unsigned int, f);
  u += 0x7fffu + ((u >> 16) & 1u);   // RNE
  return (unsigned short)(u >> 16);
}
static __device__ __forceinline__ unsigned int pack2bf(float a, float b) {
  return (unsigned int)f2bf(a) | ((unsigned int)f2bf(b) << 16);
}

// ---------------- DCLS dense 5x5 kernel construction ----------------
// k1[o][a][b] = sum_k w1[o][k] * [a == round-idx1(k)] * [b == round-idx2(k)]
__global__ void k_build_k1(const float* __restrict__ w1,
                           const float* __restrict__ p1,
                           const float* __restrict__ p2,
                           float* __restrict__ k1) {
  int t = threadIdx.x;
  if (t >= 800) return;
  int o = t / 25;
  int rem = t % 25;
  int a = rem / 5, bcol = rem % 5;
  float acc = 0.f;
  for (int k = 0; k < 26; ++k) {
    float q1 = p1[o*26 + k] + 2.0f;
    float q2 = p2[o*26 + k] + 2.0f;
    float f1 = floorf(q1), f2 = floorf(q2);
    int idx1 = (int)f1 + ((q1 - f1) >= 0.5f ? 1 : 0);
    int idx2 = (int)f2 + ((q2 - f2) >= 0.5f ? 1 : 0);
    if (idx1 == a && idx2 == bcol) acc += w1[o*26 + k];
  }
  k1[t] = acc;
}

// ---------------- weight prep: bf16 conversions ----------------
// w2b[kk][cout][cin] (kk = ky*3+kx), fc1wb[n][k] row-major
__global__ void k_prep(const float* __restrict__ w2, const float* __restrict__ fc1w,
                       unsigned short* __restrict__ w2b, unsigned short* __restrict__ fc1wb) {
  const int total = 18432 + 1605632;
  for (int i = blockIdx.x * blockDim.x + threadIdx.x; i < total; i += gridDim.x * blockDim.x) {
    if (i < 18432) {
      int cin = i & 31;
      int cout = (i >> 5) & 63;
      int kk = i >> 11;          // 0..8
      int ky = kk / 3, kx = kk % 3;
      w2b[i] = f2bf(w2[((cout*32 + cin)*3 + ky)*3 + kx]);
    } else {
      int j = i - 18432;
      fc1wb[j] = f2bf(fc1w[j]);
    }
  }
}

// ---------------- fused conv1+relu -> conv2(MFMA)+relu+maxpool ----------------
// one block = one image
__global__ __launch_bounds__(256, 1) void k_conv(
    const float* __restrict__ x, const float* __restrict__ k1g,
    const float* __restrict__ b1, const unsigned short* __restrict__ w2b,
    const float* __restrict__ b2, unsigned short* __restrict__ h3) {
  __shared__ __align__(16) float xs[1024];               // [32][32] padded input
  __shared__ __align__(16) float k1s[800];               // [32][25]
  __shared__ float b1s[32];
  __shared__ __align__(16) unsigned short h1s[30*32*32]; // [yk][xk][cin] bf16, pad y/x
  __shared__ __align__(16) unsigned short w2s[9*64*32];  // [kk][cout][cin] bf16

  const int t = threadIdx.x;
  const int bimg = blockIdx.x;

  // ---- stage ----
  for (int i = t; i < 1024; i += 256) {
    int iy = i >> 5, ix = i & 31;
    float v = 0.f;
    if (iy >= 2 && iy < 30 && ix >= 2 && ix < 30)
      v = x[bimg*784 + (iy-2)*28 + (ix-2)];
    xs[i] = v;
  }
  for (int i = t; i < 800; i += 256) k1s[i] = k1g[i];
  if (t < 32) b1s[t] = b1[t];
  {
    const u32x4* src = (const u32x4*)w2b;
    u32x4* dst = (u32x4*)w2s;
    for (int i = t; i < 2304; i += 256) dst[i] = src[i];
  }
  {
    u32x4* dst = (u32x4*)h1s;
    u32x4 z = {0u,0u,0u,0u};
    for (int i = t; i < 3840; i += 256) dst[i] = z;   // zero all (pad borders)
  }
  __syncthreads();

  // ---- conv1 (fp32 VALU): thread owns 2 channels, k1 in registers ----
  {
    const int cpair = t >> 4;     // 0..15
    const int lanep = t & 15;
    const int c0 = cpair * 2;
    float k1v0[25], k1v1[25];
    #pragma unroll
    for (int tap = 0; tap < 25; ++tap) {
      k1v0[tap] = k1s[c0*25 + tap];
      k1v1[tap] = k1s[(c0+1)*25 + tap];
    }
    const float bb0 = b1s[c0], bb1 = b1s[c0+1];
    int y = 0, xq = lanep;        // p = lanep + 16*it over 784 pixels
    for (int it = 0; it < 49; ++it) {
      float a0 = bb0, a1 = bb1;
      #pragma unroll
      for (int ky = 0; ky < 5; ++ky) {
        #pragma unroll
        for (int kx = 0; kx < 5; ++kx) {
          float xv = xs[(y+ky)*32 + xq + kx];
          a0 = fmaf(xv, k1v0[ky*5+kx], a0);
          a1 = fmaf(xv, k1v1[ky*5+kx], a1);
        }
      }
      *(unsigned int*)&h1s[((y+1)*32 + (xq+1))*32 + c0] =
          pack2bf(fmaxf(a0, 0.f), fmaxf(a1, 0.f));
      xq += 16; if (xq >= 28) { xq -= 28; y += 1; }
    }
  }
  __syncthreads();

  // ---- conv2 via MFMA 16x16x32 bf16: M=pixels(32-pad rows), N=64, K=9x32 ----
  const int lane = t & 63;
  const int wid = t >> 6;
  const int l15 = lane & 15;
  const int lk = lane >> 4;

  bf16x8 bfr[4][9];
  #pragma unroll
  for (int nt = 0; nt < 4; ++nt)
    #pragma unroll
    for (int kk = 0; kk < 9; ++kk)
      bfr[nt][kk] = *(const bf16x8*)&w2s[(kk*64 + nt*16 + l15)*32 + lk*8];

  float b2v[4];
  #pragma unroll
  for (int nt = 0; nt < 4; ++nt) b2v[nt] = b2[nt*16 + l15];

  // job = (pooled row py, x-halftile tx); each computes 2 conv rows + pools
  for (int j = wid; j < 28; j += 4) {
    const int py = j >> 1, tx = j & 1;
    float hm[4][2][2];
    #pragma unroll
    for (int yi = 0; yi < 2; ++yi) {
      const int y = py*2 + yi;
      f32x4 acc[4];
      #pragma unroll
      for (int nt = 0; nt < 4; ++nt) acc[nt] = (f32x4){0.f,0.f,0.f,0.f};
      #pragma unroll
      for (int kk = 0; kk < 9; ++kk) {
        const int ky = kk / 3, kx = kk % 3;
        int xk = tx*16 + l15 + kx;
        xk = xk > 31 ? 31 : xk;                 // clamp dummy lanes (zeros)
        bf16x8 af = *(const bf16x8*)&h1s[((y+ky)*32 + xk)*32 + lk*8];
        #pragma unroll
        for (int nt = 0; nt < 4; ++nt)
          acc[nt] = __builtin_amdgcn_mfma_f32_16x16x32_bf16(af, bfr[nt][kk], acc[nt], 0, 0, 0);
      }
      // rows of D = 4 consecutive x per lane -> bias+relu+horizontal max
      #pragma unroll
      for (int nt = 0; nt < 4; ++nt) {
        float v0 = fmaxf(acc[nt][0] + b2v[nt], 0.f);
        float v1 = fmaxf(acc[nt][1] + b2v[nt], 0.f);
        float v2 = fmaxf(acc[nt][2] + b2v[nt], 0.f);
        float v3 = fmaxf(acc[nt][3] + b2v[nt], 0.f);
        hm[nt][yi][0] = fmaxf(v0, v1);
        hm[nt][yi][1] = fmaxf(v2, v3);
      }
    }
    if (!(tx == 1 && lk == 3)) {                 // drop x>=28 dummy columns
      const int px0 = tx*8 + lk*2;
      #pragma unroll
      for (int nt = 0; nt < 4; ++nt) {
        float q0 = fmaxf(hm[nt][0][0], hm[nt][1][0]);
        float q1 = fmaxf(hm[nt][0][1], hm[nt][1][1]);
        const int c = nt*16 + l15;
        *(unsigned int*)&h3[((size_t)(bimg*64 + c)*14 + py)*14 + px0] = pack2bf(q0, q1);
      }
    }
  }
}

// ---------------- FC1 GEMM: M=2048 N=128 K=12544, K-split x4 ----------------
__global__ __launch_bounds__(64) void k_fc1(const unsigned short* __restrict__ h3,
                                            const unsigned short* __restrict__ fc1wb,
                                            float* __restrict__ h4p) {
  const int bid = blockIdx.x;        // 2048
  const int kh = bid >> 9;           // 0..3 K-chunk
  const int r = bid & 511;
  const int mtile = r >> 2;          // 0..127
  const int ntp = r & 3;             // 0..3 (2 N-tiles each)
  const int lane = threadIdx.x;
  const int l15 = lane & 15, lk = lane >> 4;

  const unsigned short* ap  = h3    + (size_t)(mtile*16 + l15)*12544 + kh*98*32 + lk*8;
  const unsigned short* b0p = fc1wb + (size_t)(ntp*32 + l15)*12544 + kh*98*32 + lk*8;
  const unsigned short* b1p = b0p + (size_t)16*12544;

  f32x4 acc0 = {0.f,0.f,0.f,0.f}, acc1 = {0.f,0.f,0.f,0.f};
  for (int ks = 0; ks < 98; ++ks) {
    bf16x8 a  = *(const bf16x8*)(ap  + ks*32);
    bf16x8 w0 = *(const bf16x8*)(b0p + ks*32);
    bf16x8 w1 = *(const bf16x8*)(b1p + ks*32);
    acc0 = __builtin_amdgcn_mfma_f32_16x16x32_bf16(a, w0, acc0, 0, 0, 0);
    acc1 = __builtin_amdgcn_mfma_f32_16x16x32_bf16(a, w1, acc1, 0, 0, 0);
  }
  float* outp = h4p + (size_t)kh * NB * 128;
  const int n0 = ntp*32 + l15;
  #pragma unroll
  for (int jj = 0; jj < 4; ++jj) {
    const int bb = mtile*16 + lk*4 + jj;
    outp[bb*128 + n0]      = acc0[jj];
    outp[bb*128 + n0 + 16] = acc1[jj];
  }
}

// ---------------- K-partial reduce + bias + relu + FC2 ----------------
__global__ __launch_bounds__(256) void k_fc2(const float* __restrict__ h4p,
                                             const float* __restrict__ fc1b,
                                             const float* __restrict__ fc2w,
                                             const float* __restrict__ fc2b,
                                             float* __restrict__ out) {
  __shared__ float hs[32*129];
  const int blk = blockIdx.x;    // 64 blocks x 32 batches
  const int t = threadIdx.x;
  for (int i = t; i < 4096; i += 256) {
    const int base = blk*4096 + i;
    float v = h4p[base] + h4p[base + 262144] + h4p[base + 2*262144] + h4p[base + 3*262144];
    v += fc1b[i & 127];
    hs[(i >> 7)*129 + (i & 127)] = fmaxf(v, 0.f);
  }
  __syncthreads();
  for (int i = t; i < 320; i += 256) {
    const int bb = i / 10, n = i % 10;
    float acc = fc2b[n];
    const float* wr = fc2w + n*128;
    const float* hr = hs + bb*129;
    #pragma unroll 8
    for (int k = 0; k < 128; ++k) acc = fmaf(hr[k], wr[k], acc);
    out[(blk*32 + bb)*10 + n] = acc;
  }
}

extern "C" void kernel_launch(void* const* d_in, const int* in_sizes, int n_in,
                              void* d_out, int out_size, void* d_ws, size_t ws_size,
                              hipStream_t stream) {
  const float* x    = (const float*)d_in[0];
  const float* w1   = (const float*)d_in[1];
  const float* p1   = (const float*)d_in[2];
  const float* p2   = (const float*)d_in[3];
  const float* b1   = (const float*)d_in[4];
  const float* w2   = (const float*)d_in[5];
  const float* b2   = (const float*)d_in[6];
  const float* fc1w = (const float*)d_in[7];
  const float* fc1b = (const float*)d_in[8];
  const float* fc2w = (const float*)d_in[9];
  const float* fc2b = (const float*)d_in[10];

  // ws layout (bytes):
  //      0: k1 f32[800]                (3200)
  //   4096: w2b bf16[9][64][32]        (36864)
  //  40960: fc1wb bf16[128][12544]     (3211264)
  // 3252224: h3 bf16[2048][64][14][14] (51380224)
  // 54632448: h4p f32[4][2048][128]    (4194304)  -> total 58826752
  if (ws_size < 58826752u) return;   // workspace too small: fail cleanly
  char* ws = (char*)d_ws;
  float* k1            = (float*)(ws + 0);
  unsigned short* w2b  = (unsigned short*)(ws + 4096);
  unsigned short* fc1wb= (unsigned short*)(ws + 40960);
  unsigned short* h3   = (unsigned short*)(ws + 3252224);
  float* h4p           = (float*)(ws + 54632448);

  k_build_k1<<<1, 832, 0, stream>>>(w1, p1, p2, k1);
  k_prep<<<2048, 256, 0, stream>>>(w2, fc1w, w2b, fc1wb);
  k_conv<<<NB, 256, 0, stream>>>(x, k1, b1, w2b, b2, h3);
  k_fc1<<<2048, 64, 0, stream>>>(h3, fc1wb, h4p);
  k_fc2<<<64, 256, 0, stream>>>(h4p, fc1b, fc2w, fc2b, (float*)d_out);
}

// Round 2
// 174.117 us; speedup vs baseline: 1.4711x; 1.4711x over previous
//
#include <hip/hip_runtime.h>
#include <hip/hip_bf16.h>

typedef __attribute__((ext_vector_type(8))) short bf16x8;
typedef __attribute__((ext_vector_type(4))) float f32x4;
typedef __attribute__((ext_vector_type(4))) unsigned int u32x4;

#define NB 2048
#define FC1_KC 1568   // K per kh-chunk (12544/8)

static __device__ __forceinline__ unsigned short f2bf(float f) {
  unsigned int u = __builtin_bit_cast(unsigned int, f);
  u += 0x7fffu + ((u >> 16) & 1u);   // RNE
  return (unsigned short)(u >> 16);
}
static __device__ __forceinline__ unsigned int pack2bf(float a, float b) {
  return (unsigned int)f2bf(a) | ((unsigned int)f2bf(b) << 16);
}

// ---------------- DCLS dense 5x5 kernel construction ----------------
__global__ void k_build_k1(const float* __restrict__ w1,
                           const float* __restrict__ p1,
                           const float* __restrict__ p2,
                           float* __restrict__ k1) {
  int t = threadIdx.x;
  if (t >= 800) return;
  int o = t / 25;
  int rem = t % 25;
  int a = rem / 5, bcol = rem % 5;
  float acc = 0.f;
  for (int k = 0; k < 26; ++k) {
    float q1 = p1[o*26 + k] + 2.0f;
    float q2 = p2[o*26 + k] + 2.0f;
    float f1 = floorf(q1), f2 = floorf(q2);
    int idx1 = (int)f1 + ((q1 - f1) >= 0.5f ? 1 : 0);
    int idx2 = (int)f2 + ((q2 - f2) >= 0.5f ? 1 : 0);
    if (idx1 == a && idx2 == bcol) acc += w1[o*26 + k];
  }
  k1[t] = acc;
}

// ---------------- weight prep: bf16 conversions ----------------
// w2b[kk][cout][cin] (kk = ky*3+kx), fc1wb[n][k] row-major
__global__ void k_prep(const float* __restrict__ w2, const float* __restrict__ fc1w,
                       unsigned short* __restrict__ w2b, unsigned short* __restrict__ fc1wb) {
  const int total = 18432 + 1605632;
  for (int i = blockIdx.x * blockDim.x + threadIdx.x; i < total; i += gridDim.x * blockDim.x) {
    if (i < 18432) {
      int cin = i & 31;
      int cout = (i >> 5) & 63;
      int kk = i >> 11;          // 0..8
      int ky = kk / 3, kx = kk % 3;
      w2b[i] = f2bf(w2[((cout*32 + cin)*3 + ky)*3 + kx]);
    } else {
      int j = i - 18432;
      fc1wb[j] = f2bf(fc1w[j]);
    }
  }
}

// ---------------- fused conv1+relu -> conv2(MFMA)+relu+maxpool ----------------
// one block = one image; 2 blocks/CU (LDS 67.3 KB, VGPR <= 128)
__global__ __launch_bounds__(256, 2) void k_conv(
    const float* __restrict__ x, const float* __restrict__ k1g,
    const float* __restrict__ b1, const unsigned short* __restrict__ w2b,
    const float* __restrict__ b2, unsigned short* __restrict__ h3) {
  __shared__ __align__(16) float xs[1024];               // [32][32] padded input
  __shared__ __align__(16) float k1s[800];               // [32][25]
  __shared__ float b1s[32];
  __shared__ __align__(16) unsigned short h1s[30*32*32]; // [yk][xk][cin] bf16

  const int t = threadIdx.x;
  const int bimg = blockIdx.x;

  // ---- stage ----
  for (int i = t; i < 1024; i += 256) {
    int iy = i >> 5, ix = i & 31;
    float v = 0.f;
    if (iy >= 2 && iy < 30 && ix >= 2 && ix < 30)
      v = x[bimg*784 + (iy-2)*28 + (ix-2)];
    xs[i] = v;
  }
  for (int i = t; i < 800; i += 256) k1s[i] = k1g[i];
  if (t < 32) b1s[t] = b1[t];
  {
    u32x4* dst = (u32x4*)h1s;
    u32x4 z = {0u,0u,0u,0u};
    for (int i = t; i < 3840; i += 256) dst[i] = z;   // zero all (pad borders)
  }
  __syncthreads();

  // ---- conv1 (fp32 VALU, register sliding window over 14-px strips) ----
  // job = sid*16 + cpair; sid = (y, xhalf); 896 jobs
  for (int j = t; j < 896; j += 256) {
    const int cpair = j & 15;
    const int sid = j >> 4;
    const int y = sid >> 1;
    const int x0 = (sid & 1) * 14;
    const int c0 = cpair * 2;
    float tap0[25], tap1[25];
    #pragma unroll
    for (int u = 0; u < 25; ++u) {
      tap0[u] = k1s[c0*25 + u];
      tap1[u] = k1s[c0*25 + 25 + u];
    }
    const float bb0 = b1s[c0], bb1 = b1s[c0+1];
    float xw[5][5];                      // [col mod 5][ky]
    #pragma unroll
    for (int c = 0; c < 4; ++c)
      #pragma unroll
      for (int ky = 0; ky < 5; ++ky)
        xw[c][ky] = xs[(y + ky)*32 + x0 + c];
    #pragma unroll
    for (int i = 0; i < 14; ++i) {
      const int cnew = (i + 4) % 5;
      #pragma unroll
      for (int ky = 0; ky < 5; ++ky) xw[cnew][ky] = xs[(y + ky)*32 + x0 + i + 4];
      float a0 = bb0, a1 = bb1;
      #pragma unroll
      for (int kx = 0; kx < 5; ++kx) {
        const int cc = (i + kx) % 5;
        #pragma unroll
        for (int ky = 0; ky < 5; ++ky) {
          a0 = fmaf(xw[cc][ky], tap0[ky*5 + kx], a0);
          a1 = fmaf(xw[cc][ky], tap1[ky*5 + kx], a1);
        }
      }
      const int pixel = (y + 1)*32 + x0 + i + 1;
      *(unsigned int*)&h1s[pixel*32 + c0] =
          pack2bf(fmaxf(a0, 0.f), fmaxf(a1, 0.f));
    }
  }
  __syncthreads();

  // ---- conv2 via MFMA 16x16x32 bf16: B frags streamed from global (L1-hot) ----
  const int lane = t & 63;
  const int wid = t >> 6;
  const int l15 = lane & 15;
  const int lk = lane >> 4;

  float b2v[4];
  #pragma unroll
  for (int nt = 0; nt < 4; ++nt) b2v[nt] = b2[nt*16 + l15];

  for (int j = wid; j < 28; j += 4) {
    const int py = j >> 1, tx = j & 1;
    f32x4 acc[2][4];
    #pragma unroll
    for (int yi = 0; yi < 2; ++yi)
      #pragma unroll
      for (int nt = 0; nt < 4; ++nt) acc[yi][nt] = (f32x4){0.f,0.f,0.f,0.f};

    #pragma unroll
    for (int kk = 0; kk < 9; ++kk) {
      const int ky = kk / 3, kx = kk % 3;
      bf16x8 bf[4];
      #pragma unroll
      for (int nt = 0; nt < 4; ++nt)
        bf[nt] = *(const bf16x8*)&w2b[(kk*64 + nt*16 + l15)*32 + lk*8];
      int xk = tx*16 + l15 + kx;
      xk = xk > 31 ? 31 : xk;                 // clamp dummy lanes (zeros)
      #pragma unroll
      for (int yi = 0; yi < 2; ++yi) {
        const int y = py*2 + yi;
        bf16x8 af = *(const bf16x8*)&h1s[((y+ky)*32 + xk)*32 + lk*8];
        #pragma unroll
        for (int nt = 0; nt < 4; ++nt)
          acc[yi][nt] = __builtin_amdgcn_mfma_f32_16x16x32_bf16(af, bf[nt], acc[yi][nt], 0, 0, 0);
      }
    }
    // bias + relu + 2x2 maxpool in-register, write bf16
    float hm[4][2][2];
    #pragma unroll
    for (int yi = 0; yi < 2; ++yi)
      #pragma unroll
      for (int nt = 0; nt < 4; ++nt) {
        float v0 = fmaxf(acc[yi][nt][0] + b2v[nt], 0.f);
        float v1 = fmaxf(acc[yi][nt][1] + b2v[nt], 0.f);
        float v2 = fmaxf(acc[yi][nt][2] + b2v[nt], 0.f);
        float v3 = fmaxf(acc[yi][nt][3] + b2v[nt], 0.f);
        hm[nt][yi][0] = fmaxf(v0, v1);
        hm[nt][yi][1] = fmaxf(v2, v3);
      }
    if (!(tx == 1 && lk == 3)) {                 // drop x>=28 dummy columns
      const int px0 = tx*8 + lk*2;
      #pragma unroll
      for (int nt = 0; nt < 4; ++nt) {
        float q0 = fmaxf(hm[nt][0][0], hm[nt][1][0]);
        float q1 = fmaxf(hm[nt][0][1], hm[nt][1][1]);
        const int c = nt*16 + l15;
        *(unsigned int*)&h3[((size_t)(bimg*64 + c)*14 + py)*14 + px0] = pack2bf(q0, q1);
      }
    }
  }
}

// ---------------- FC1 GEMM: M=2048 N=128 K=12544, kh=8, A staged in LDS ----------------
__global__ __launch_bounds__(256) void k_fc1(const unsigned short* __restrict__ h3,
                                             const unsigned short* __restrict__ fc1wb,
                                             float* __restrict__ h4p) {
  __shared__ __align__(16) unsigned short As[16 * FC1_KC];   // 50176 B
  const int bid = blockIdx.x;            // 128 mtiles x 8 kh
  const int mtile = bid >> 3, kh = bid & 7;
  const int t = threadIdx.x, lane = t & 63, w = t >> 6;
  const unsigned short* Ag = h3 + (size_t)(mtile*16)*12544 + kh*FC1_KC;

  // stage A: per row 3 x 1KB async direct-to-LDS + 64B tail via regs
  #pragma unroll
  for (int rr = 0; rr < 4; ++rr) {
    const int r = w*4 + rr;
    const unsigned short* rowg = Ag + (size_t)r*12544 + lane*8;
    #pragma unroll
    for (int p = 0; p < 3; ++p) {
      __builtin_amdgcn_global_load_lds(
          (const __attribute__((address_space(1))) unsigned int*)(rowg + p*512),
          (__attribute__((address_space(3))) unsigned int*)&As[r*FC1_KC + p*512],
          16, 0, 0);
    }
  }
  {
    const int r = t >> 4, o = (t & 15) * 2;
    *(unsigned int*)&As[r*FC1_KC + 1536 + o] =
        *(const unsigned int*)(Ag + (size_t)r*12544 + 1536 + o);
  }
  __syncthreads();

  const int l15 = lane & 15, lk = lane >> 4;
  const unsigned short* ap  = As + l15*FC1_KC + lk*8;
  const unsigned short* b0p = fc1wb + (size_t)(w*32 + l15)*12544 + kh*FC1_KC + lk*8;
  const unsigned short* b1p = b0p + (size_t)16*12544;

  f32x4 acc0 = {0.f,0.f,0.f,0.f}, acc1 = {0.f,0.f,0.f,0.f};
  for (int ks = 0; ks < 49; ++ks) {
    bf16x8 a  = *(const bf16x8*)(ap  + ks*32);
    bf16x8 w0 = *(const bf16x8*)(b0p + ks*32);
    bf16x8 w1 = *(const bf16x8*)(b1p + ks*32);
    acc0 = __builtin_amdgcn_mfma_f32_16x16x32_bf16(a, w0, acc0, 0, 0, 0);
    acc1 = __builtin_amdgcn_mfma_f32_16x16x32_bf16(a, w1, acc1, 0, 0, 0);
  }
  float* outp = h4p + (size_t)kh * NB * 128;
  const int n0 = w*32 + l15;
  #pragma unroll
  for (int jj = 0; jj < 4; ++jj) {
    const int bb = mtile*16 + lk*4 + jj;
    outp[bb*128 + n0]      = acc0[jj];
    outp[bb*128 + n0 + 16] = acc1[jj];
  }
}

// ---------------- K-partial reduce + bias + relu + FC2 ----------------
__global__ __launch_bounds__(256) void k_fc2(const float* __restrict__ h4p,
                                             const float* __restrict__ fc1b,
                                             const float* __restrict__ fc2w,
                                             const float* __restrict__ fc2b,
                                             float* __restrict__ out) {
  __shared__ float hs[32*129];
  const int blk = blockIdx.x;    // 64 blocks x 32 batches
  const int t = threadIdx.x;
  for (int i = t; i < 4096; i += 256) {
    const int base = blk*4096 + i;
    float v = 0.f;
    #pragma unroll
    for (int kh = 0; kh < 8; ++kh) v += h4p[base + kh*262144];
    v += fc1b[i & 127];
    hs[(i >> 7)*129 + (i & 127)] = fmaxf(v, 0.f);
  }
  __syncthreads();
  for (int i = t; i < 320; i += 256) {
    const int bb = i / 10, n = i % 10;
    float acc = fc2b[n];
    const float* wr = fc2w + n*128;
    const float* hr = hs + bb*129;
    #pragma unroll 8
    for (int k = 0; k < 128; ++k) acc = fmaf(hr[k], wr[k], acc);
    out[(blk*32 + bb)*10 + n] = acc;
  }
}

extern "C" void kernel_launch(void* const* d_in, const int* in_sizes, int n_in,
                              void* d_out, int out_size, void* d_ws, size_t ws_size,
                              hipStream_t stream) {
  const float* x    = (const float*)d_in[0];
  const float* w1   = (const float*)d_in[1];
  const float* p1   = (const float*)d_in[2];
  const float* p2   = (const float*)d_in[3];
  const float* b1   = (const float*)d_in[4];
  const float* w2   = (const float*)d_in[5];
  const float* b2   = (const float*)d_in[6];
  const float* fc1w = (const float*)d_in[7];
  const float* fc1b = (const float*)d_in[8];
  const float* fc2w = (const float*)d_in[9];
  const float* fc2b = (const float*)d_in[10];

  // ws layout (bytes):
  //        0: k1 f32[800]                (3200)
  //     4096: w2b bf16[9][64][32]        (36864)
  //    40960: fc1wb bf16[128][12544]     (3211264)
  //  3252224: h3 bf16[2048][64][14][14]  (51380224)
  // 54632448: h4p f32[8][2048][128]      (8388608)  -> total 63021056
  if (ws_size < 63021056u) return;
  char* ws = (char*)d_ws;
  float* k1            = (float*)(ws + 0);
  unsigned short* w2b  = (unsigned short*)(ws + 4096);
  unsigned short* fc1wb= (unsigned short*)(ws + 40960);
  unsigned short* h3   = (unsigned short*)(ws + 3252224);
  float* h4p           = (float*)(ws + 54632448);

  k_build_k1<<<1, 832, 0, stream>>>(w1, p1, p2, k1);
  k_prep<<<2048, 256, 0, stream>>>(w2, fc1w, w2b, fc1wb);
  k_conv<<<NB, 256, 0, stream>>>(x, k1, b1, w2b, b2, h3);
  k_fc1<<<1024, 256, 0, stream>>>(h3, fc1wb, h4p);
  k_fc2<<<64, 256, 0, stream>>>(h4p, fc1b, fc2w, fc2b, (float*)d_out);
}

// Round 3
// 164.804 us; speedup vs baseline: 1.5542x; 1.0565x over previous
//
#include <hip/hip_runtime.h>
#include <hip/hip_bf16.h>

typedef __attribute__((ext_vector_type(8))) short bf16x8;
typedef __attribute__((ext_vector_type(4))) float f32x4;
typedef __attribute__((ext_vector_type(4))) unsigned int u32x4;

#define NB 2048
#define FC1_KC 1568   // K per kh-chunk (12544/8)

static __device__ __forceinline__ unsigned short f2bf(float f) {
  unsigned int u = __builtin_bit_cast(unsigned int, f);
  u += 0x7fffu + ((u >> 16) & 1u);   // RNE
  return (unsigned short)(u >> 16);
}
static __device__ __forceinline__ unsigned int pack2bf(float a, float b) {
  return (unsigned int)f2bf(a) | ((unsigned int)f2bf(b) << 16);
}

// ---------------- weight prep: bf16 conversions + DCLS kernel build ----------------
// region 0: w2b[kk][cout][cin]; region 1: fc1wb[n][k]; region 2: k1 dense 5x5
__global__ void k_prep(const float* __restrict__ w2, const float* __restrict__ fc1w,
                       const float* __restrict__ w1, const float* __restrict__ p1,
                       const float* __restrict__ p2,
                       unsigned short* __restrict__ w2b, unsigned short* __restrict__ fc1wb,
                       float* __restrict__ k1) {
  const int total = 18432 + 1605632 + 800;
  for (int i = blockIdx.x * blockDim.x + threadIdx.x; i < total; i += gridDim.x * blockDim.x) {
    if (i < 18432) {
      int cin = i & 31;
      int cout = (i >> 5) & 63;
      int kk = i >> 11;          // 0..8
      int ky = kk / 3, kx = kk % 3;
      w2b[i] = f2bf(w2[((cout*32 + cin)*3 + ky)*3 + kx]);
    } else if (i < 18432 + 1605632) {
      int j = i - 18432;
      fc1wb[j] = f2bf(fc1w[j]);
    } else {
      int t = i - (18432 + 1605632);   // 0..799
      int o = t / 25;
      int rem = t % 25;
      int a = rem / 5, bcol = rem % 5;
      float acc = 0.f;
      for (int k = 0; k < 26; ++k) {
        float q1 = p1[o*26 + k] + 2.0f;
        float q2 = p2[o*26 + k] + 2.0f;
        float f1 = floorf(q1), f2 = floorf(q2);
        int idx1 = (int)f1 + ((q1 - f1) >= 0.5f ? 1 : 0);
        int idx2 = (int)f2 + ((q2 - f2) >= 0.5f ? 1 : 0);
        if (idx1 == a && idx2 == bcol) acc += w1[o*26 + k];
      }
      k1[t] = acc;
    }
  }
}

// ---------------- fused conv1+relu -> conv2(MFMA)+relu+maxpool ----------------
// one block = one image; 2 blocks/CU (LDS 67.3 KB)
// h1s layout: pixel-major, 4x 16B cin-blocks per pixel, XOR-swizzled:
//   elem(pixel, cin) -> pixel*32 + ((cin>>3) ^ ((pixel>>1)&3))*8 + (cin&7)
__global__ __launch_bounds__(256, 2) void k_conv(
    const float* __restrict__ x, const float* __restrict__ k1g,
    const float* __restrict__ b1, const unsigned short* __restrict__ w2b,
    const float* __restrict__ b2, unsigned short* __restrict__ h3) {
  __shared__ __align__(16) float xs[1024];               // [32][32] padded input
  __shared__ __align__(16) float k1s[800];               // [32][25]
  __shared__ float b1s[32];
  __shared__ __align__(16) unsigned short h1s[30*32*32]; // swizzled (see above)

  const int t = threadIdx.x;
  const int bimg = blockIdx.x;
  const int lane = t & 63;
  const int wid = t >> 6;
  const int l15 = lane & 15;
  const int lk = lane >> 4;

  // ---- stage ----
  for (int i = t; i < 1024; i += 256) {
    int iy = i >> 5, ix = i & 31;
    float v = 0.f;
    if (iy >= 2 && iy < 30 && ix >= 2 && ix < 30)
      v = x[bimg*784 + (iy-2)*28 + (ix-2)];
    xs[i] = v;
  }
  for (int i = t; i < 800; i += 256) k1s[i] = k1g[i];
  if (t < 32) b1s[t] = b1[t];
  {
    u32x4* dst = (u32x4*)h1s;
    u32x4 z = {0u,0u,0u,0u};
    for (int i = t; i < 3840; i += 256) dst[i] = z;   // zero all (pad borders)
  }
  __syncthreads();

  // ---- conv1 (fp32 VALU, register sliding window; taps hoisted) ----
  {
    const int cpair = t & 15;
    const int c0 = cpair * 2;
    const int g = c0 >> 3;           // 16B-block index of this cin pair
    const int goff = c0 & 7;
    float tap0[25], tap1[25];
    #pragma unroll
    for (int u = 0; u < 25; ++u) {
      tap0[u] = k1s[c0*25 + u];
      tap1[u] = k1s[c0*25 + 25 + u];
    }
    const float bb0 = b1s[c0], bb1 = b1s[c0+1];
    for (int sid = t >> 4; sid < 56; sid += 16) {
      const int y = sid >> 1;
      const int x0 = (sid & 1) * 14;
      float xw[5][5];                      // [col mod 5][ky]
      #pragma unroll
      for (int c = 0; c < 4; ++c)
        #pragma unroll
        for (int ky = 0; ky < 5; ++ky)
          xw[c][ky] = xs[(y + ky)*32 + x0 + c];
      #pragma unroll
      for (int i = 0; i < 14; ++i) {
        const int cnew = (i + 4) % 5;
        #pragma unroll
        for (int ky = 0; ky < 5; ++ky) xw[cnew][ky] = xs[(y + ky)*32 + x0 + i + 4];
        float a0 = bb0, a1 = bb1;
        #pragma unroll
        for (int kx = 0; kx < 5; ++kx) {
          const int cc = (i + kx) % 5;
          #pragma unroll
          for (int ky = 0; ky < 5; ++ky) {
            a0 = fmaf(xw[cc][ky], tap0[ky*5 + kx], a0);
            a1 = fmaf(xw[cc][ky], tap1[ky*5 + kx], a1);
          }
        }
        const int pixel = (y + 1)*32 + x0 + i + 1;
        const int blk = g ^ ((pixel >> 1) & 3);
        *(unsigned int*)&h1s[pixel*32 + blk*8 + goff] =
            pack2bf(fmaxf(a0, 0.f), fmaxf(a1, 0.f));
      }
    }
  }

  // ---- conv2 B-fragments: load ONCE into VGPRs (wave owns an nt-pair) ----
  const int ntp = wid & 1;      // couts ntp*32 .. ntp*32+31
  const int tx  = wid >> 1;     // x half-tile, wave-uniform
  bf16x8 bfr[2][9];
  #pragma unroll
  for (int nn = 0; nn < 2; ++nn)
    #pragma unroll
    for (int kk = 0; kk < 9; ++kk)
      bfr[nn][kk] = *(const bf16x8*)&w2b[(kk*64 + (ntp*2+nn)*16 + l15)*32 + lk*8];
  float b2v[2];
  b2v[0] = b2[ntp*32 + l15];
  b2v[1] = b2[ntp*32 + 16 + l15];
  __syncthreads();

  // ---- conv2 via MFMA 16x16x32 bf16 ----
  for (int py = 0; py < 14; ++py) {
    f32x4 acc[2][2];
    #pragma unroll
    for (int yi = 0; yi < 2; ++yi)
      #pragma unroll
      for (int nn = 0; nn < 2; ++nn) acc[yi][nn] = (f32x4){0.f,0.f,0.f,0.f};

    #pragma unroll
    for (int kx = 0; kx < 3; ++kx) {
      int xk = tx*16 + l15 + kx;
      xk = xk > 31 ? 31 : xk;                 // clamp dummy lanes (zeros)
      bf16x8 af[4];                           // rows py*2 + (yi+ky)
      #pragma unroll
      for (int r = 0; r < 4; ++r) {
        const int pixel = (py*2 + r)*32 + xk;
        af[r] = *(const bf16x8*)&h1s[pixel*32 + (lk ^ ((pixel >> 1) & 3))*8];
      }
      #pragma unroll
      for (int ky = 0; ky < 3; ++ky)
        #pragma unroll
        for (int yi = 0; yi < 2; ++yi)
          #pragma unroll
          for (int nn = 0; nn < 2; ++nn)
            acc[yi][nn] = __builtin_amdgcn_mfma_f32_16x16x32_bf16(
                af[yi+ky], bfr[nn][ky*3+kx], acc[yi][nn], 0, 0, 0);
    }
    // bias + relu + 2x2 maxpool in-register, write bf16
    float hm[2][2][2];   // [nn][yi][xpair]
    #pragma unroll
    for (int yi = 0; yi < 2; ++yi)
      #pragma unroll
      for (int nn = 0; nn < 2; ++nn) {
        float v0 = fmaxf(acc[yi][nn][0] + b2v[nn], 0.f);
        float v1 = fmaxf(acc[yi][nn][1] + b2v[nn], 0.f);
        float v2 = fmaxf(acc[yi][nn][2] + b2v[nn], 0.f);
        float v3 = fmaxf(acc[yi][nn][3] + b2v[nn], 0.f);
        hm[nn][yi][0] = fmaxf(v0, v1);
        hm[nn][yi][1] = fmaxf(v2, v3);
      }
    if (!(tx == 1 && lk == 3)) {                 // drop x>=28 dummy columns
      const int px0 = tx*8 + lk*2;
      #pragma unroll
      for (int nn = 0; nn < 2; ++nn) {
        float q0 = fmaxf(hm[nn][0][0], hm[nn][1][0]);
        float q1 = fmaxf(hm[nn][0][1], hm[nn][1][1]);
        const int c = ntp*32 + nn*16 + l15;
        *(unsigned int*)&h3[((size_t)(bimg*64 + c)*14 + py)*14 + px0] = pack2bf(q0, q1);
      }
    }
  }
}

// ---------------- FC1 GEMM: M=2048 N=128 K=12544, kh=8, A staged in LDS ----------------
// As swizzled in 16B blocks: row r, block b stored at slot b ^ (r&7) (b<192; tail linear)
__global__ __launch_bounds__(256) void k_fc1(const unsigned short* __restrict__ h3,
                                             const unsigned short* __restrict__ fc1wb,
                                             float* __restrict__ h4p) {
  __shared__ __align__(16) unsigned short As[16 * FC1_KC];   // 50176 B
  const int bid = blockIdx.x;            // 128 mtiles x 8 kh
  const int mtile = bid >> 3, kh = bid & 7;
  const int t = threadIdx.x, lane = t & 63, w = t >> 6;
  const unsigned short* Ag = h3 + (size_t)(mtile*16)*12544 + kh*FC1_KC;

  // stage A: 3 x 1KB async direct-to-LDS per row (source pre-swizzled) + 64B tail
  #pragma unroll
  for (int rr = 0; rr < 4; ++rr) {
    const int r = w*4 + rr;
    const int f = r & 7;
    const unsigned short* rowg = Ag + (size_t)r*12544 + ((lane ^ f) * 8);
    #pragma unroll
    for (int p = 0; p < 3; ++p) {
      __builtin_amdgcn_global_load_lds(
          (const __attribute__((address_space(1))) unsigned int*)(rowg + p*512),
          (__attribute__((address_space(3))) unsigned int*)&As[r*FC1_KC + p*512],
          16, 0, 0);
    }
  }
  {
    const int r = t >> 4, o = (t & 15) * 2;
    *(unsigned int*)&As[r*FC1_KC + 1536 + o] =
        *(const unsigned int*)(Ag + (size_t)r*12544 + 1536 + o);
  }
  __syncthreads();

  const int l15 = lane & 15, lk = lane >> 4;
  const int swz = l15 & 7;
  const unsigned short* b0p = fc1wb + (size_t)(w*32 + l15)*12544 + kh*FC1_KC + lk*8;
  const unsigned short* b1p = b0p + (size_t)16*12544;

  f32x4 acc0 = {0.f,0.f,0.f,0.f}, acc1 = {0.f,0.f,0.f,0.f};
  #pragma unroll 7
  for (int ks = 0; ks < 49; ++ks) {
    const int b = ks*4 + lk;
    const int s = (ks < 48) ? (b ^ swz) : b;
    bf16x8 a  = *(const bf16x8*)&As[l15*FC1_KC + s*8];
    bf16x8 w0 = *(const bf16x8*)(b0p + ks*32);
    bf16x8 w1 = *(const bf16x8*)(b1p + ks*32);
    acc0 = __builtin_amdgcn_mfma_f32_16x16x32_bf16(a, w0, acc0, 0, 0, 0);
    acc1 = __builtin_amdgcn_mfma_f32_16x16x32_bf16(a, w1, acc1, 0, 0, 0);
  }
  float* outp = h4p + (size_t)kh * NB * 128;
  const int n0 = w*32 + l15;
  #pragma unroll
  for (int jj = 0; jj < 4; ++jj) {
    const int bb = mtile*16 + lk*4 + jj;
    outp[bb*128 + n0]      = acc0[jj];
    outp[bb*128 + n0 + 16] = acc1[jj];
  }
}

// ---------------- K-partial reduce + bias + relu + FC2 ----------------
__global__ __launch_bounds__(256) void k_fc2(const float* __restrict__ h4p,
                                             const float* __restrict__ fc1b,
                                             const float* __restrict__ fc2w,
                                             const float* __restrict__ fc2b,
                                             float* __restrict__ out) {
  __shared__ float hs[32*129];
  const int blk = blockIdx.x;    // 64 blocks x 32 batches
  const int t = threadIdx.x;
  for (int i = t; i < 4096; i += 256) {
    const int base = blk*4096 + i;
    float v = 0.f;
    #pragma unroll
    for (int kh = 0; kh < 8; ++kh) v += h4p[base + kh*262144];
    v += fc1b[i & 127];
    hs[(i >> 7)*129 + (i & 127)] = fmaxf(v, 0.f);
  }
  __syncthreads();
  for (int i = t; i < 320; i += 256) {
    const int bb = i / 10, n = i % 10;
    float acc = fc2b[n];
    const float* wr = fc2w + n*128;
    const float* hr = hs + bb*129;
    #pragma unroll 8
    for (int k = 0; k < 128; ++k) acc = fmaf(hr[k], wr[k], acc);
    out[(blk*32 + bb)*10 + n] = acc;
  }
}

extern "C" void kernel_launch(void* const* d_in, const int* in_sizes, int n_in,
                              void* d_out, int out_size, void* d_ws, size_t ws_size,
                              hipStream_t stream) {
  const float* x    = (const float*)d_in[0];
  const float* w1   = (const float*)d_in[1];
  const float* p1   = (const float*)d_in[2];
  const float* p2   = (const float*)d_in[3];
  const float* b1   = (const float*)d_in[4];
  const float* w2   = (const float*)d_in[5];
  const float* b2   = (const float*)d_in[6];
  const float* fc1w = (const float*)d_in[7];
  const float* fc1b = (const float*)d_in[8];
  const float* fc2w = (const float*)d_in[9];
  const float* fc2b = (const float*)d_in[10];

  // ws layout (bytes):
  //        0: k1 f32[800]                (3200)
  //     4096: w2b bf16[9][64][32]        (36864)
  //    40960: fc1wb bf16[128][12544]     (3211264)
  //  3252224: h3 bf16[2048][64][14][14]  (51380224)
  // 54632448: h4p f32[8][2048][128]      (8388608)  -> total 63021056
  if (ws_size < 63021056u) return;
  char* ws = (char*)d_ws;
  float* k1            = (float*)(ws + 0);
  unsigned short* w2b  = (unsigned short*)(ws + 4096);
  unsigned short* fc1wb= (unsigned short*)(ws + 40960);
  unsigned short* h3   = (unsigned short*)(ws + 3252224);
  float* h4p           = (float*)(ws + 54632448);

  k_prep<<<2048, 256, 0, stream>>>(w2, fc1w, w1, p1, p2, w2b, fc1wb, k1);
  k_conv<<<NB, 256, 0, stream>>>(x, k1, b1, w2b, b2, h3);
  k_fc1<<<1024, 256, 0, stream>>>(h3, fc1wb, h4p);
  k_fc2<<<64, 256, 0, stream>>>(h4p, fc1b, fc2w, fc2b, (float*)d_out);
}

// Round 4
// 135.768 us; speedup vs baseline: 1.8866x; 1.2139x over previous
//
#include <hip/hip_runtime.h>
#include <hip/hip_bf16.h>

typedef __attribute__((ext_vector_type(8))) short bf16x8;
typedef __attribute__((ext_vector_type(4))) float f32x4;
typedef __attribute__((ext_vector_type(4))) unsigned int u32x4;
typedef __attribute__((ext_vector_type(2))) unsigned int u32x2;

#define NB 2048
#define FC1_KC 1568   // K per kh-chunk (12544/8)

static __device__ __forceinline__ unsigned short f2bf(float f) {
  unsigned int u = __builtin_bit_cast(unsigned int, f);
  u += 0x7fffu + ((u >> 16) & 1u);   // RNE
  return (unsigned short)(u >> 16);
}
// HW packed f32->bf16 (RNE), two values into one dword
static __device__ __forceinline__ unsigned int cvtpk(float lo, float hi) {
  unsigned int r;
  asm("v_cvt_pk_bf16_f32 %0, %1, %2" : "=v"(r) : "v"(lo), "v"(hi));
  return r;
}

// ---------------- weight prep: bf16 conversions + DCLS kernel build ----------------
// region 0: w2b[kk][cout][cin]; region 1: fc1wb[n][k]; region 2: k1b[cout][tap32] bf16
__global__ void k_prep(const float* __restrict__ w2, const float* __restrict__ fc1w,
                       const float* __restrict__ w1, const float* __restrict__ p1,
                       const float* __restrict__ p2,
                       unsigned short* __restrict__ w2b, unsigned short* __restrict__ fc1wb,
                       unsigned short* __restrict__ k1b) {
  const int total = 18432 + 1605632 + 1024;
  for (int i = blockIdx.x * blockDim.x + threadIdx.x; i < total; i += gridDim.x * blockDim.x) {
    if (i < 18432) {
      int cin = i & 31;
      int cout = (i >> 5) & 63;
      int kk = i >> 11;          // 0..8
      int ky = kk / 3, kx = kk % 3;
      w2b[i] = f2bf(w2[((cout*32 + cin)*3 + ky)*3 + kx]);
    } else if (i < 18432 + 1605632) {
      int j = i - 18432;
      fc1wb[j] = f2bf(fc1w[j]);
    } else {
      int t = i - (18432 + 1605632);   // 0..1023
      int o = t >> 5, tap = t & 31;
      unsigned short r = 0;
      if (tap < 25) {
        int a = tap / 5, bcol = tap % 5;
        float acc = 0.f;
        for (int k = 0; k < 26; ++k) {
          float q1 = p1[o*26 + k] + 2.0f;
          float q2 = p2[o*26 + k] + 2.0f;
          float f1 = floorf(q1), f2 = floorf(q2);
          int idx1 = (int)f1 + ((q1 - f1) >= 0.5f ? 1 : 0);
          int idx2 = (int)f2 + ((q2 - f2) >= 0.5f ? 1 : 0);
          if (idx1 == a && idx2 == bcol) acc += w1[o*26 + k];
        }
        r = f2bf(acc);
      }
      k1b[t] = r;
    }
  }
}

// ---------------- fused conv1(MFMA)+relu -> conv2(MFMA)+relu+maxpool ----------------
// one block = one image; 3 blocks/CU (LDS 37.4 KB); image processed in 2 y-halves
// h1s layout: pixel-major, 4x 16B cin-blocks per pixel, XOR-swizzled:
//   elem(pixel, cin) -> pixel*32 + ((cin>>3) ^ ((pixel>>1)&3))*8 + (cin&7)
__global__ __launch_bounds__(256, 3) void k_conv(
    const float* __restrict__ x, const unsigned short* __restrict__ k1b,
    const float* __restrict__ b1, const unsigned short* __restrict__ w2b,
    const float* __restrict__ b2, unsigned short* __restrict__ h3) {
  __shared__ __align__(16) float xs[32*36];              // padded input, stride 36
  __shared__ __align__(16) unsigned short h1s[16*32*32]; // one y-half, swizzled

  const int t = threadIdx.x;
  const int bimg = blockIdx.x;
  const int lane = t & 63;
  const int wid = t >> 6;
  const int l15 = lane & 15;
  const int lk = lane >> 4;

  // ---- stage x into xs (zero border) ----
  for (int i = t; i < 1152; i += 256) {
    int iy = i / 36, ix = i - iy*36;
    float v = 0.f;
    if (iy >= 2 && iy < 30 && ix >= 2 && ix < 30)
      v = x[bimg*784 + (iy-2)*28 + (ix-2)];
    xs[i] = v;
  }

  // ---- conv1 operands (registers) ----
  int off[8];                       // per-lane im2col tap offsets (taps>=25 clamp: A rows are 0 there)
  #pragma unroll
  for (int j = 0; j < 8; ++j) {
    int tp = lk*8 + j; tp = tp > 24 ? 24 : tp;
    int ky = tp / 5;
    off[j] = ky*36 + (tp - ky*5);
  }
  const bf16x8 k1a0 = *(const bf16x8*)&k1b[l15*32 + lk*8];
  const bf16x8 k1a1 = *(const bf16x8*)&k1b[(16 + l15)*32 + lk*8];
  float b1v[2][4];
  #pragma unroll
  for (int nt = 0; nt < 2; ++nt)
    #pragma unroll
    for (int r = 0; r < 4; ++r)
      b1v[nt][r] = b1[nt*16 + lk*4 + r];

  // ---- conv2 operands (registers) ----
  const int ntp = wid & 1;      // couts ntp*32 .. ntp*32+31
  const int tx  = wid >> 1;     // x half-tile (wave-uniform)
  bf16x8 bfr[2][9];
  #pragma unroll
  for (int nn = 0; nn < 2; ++nn)
    #pragma unroll
    for (int kk = 0; kk < 9; ++kk)
      bfr[nn][kk] = *(const bf16x8*)&w2b[(kk*64 + (ntp*2+nn)*16 + l15)*32 + lk*8];
  float b2v[2];
  b2v[0] = b2[ntp*32 + l15];
  b2v[1] = b2[ntp*32 + 16 + l15];
  int colOff[3];                // byte offsets into an h1s row (swizzle is row-independent)
  #pragma unroll
  for (int kx = 0; kx < 3; ++kx) {
    int xk = tx*16 + l15 + kx; xk = xk > 31 ? 31 : xk;   // clamped dummies read zero pads
    colOff[kx] = xk*64 + ((lk ^ ((xk >> 1) & 3)) << 4);
  }

  __syncthreads();

  for (int half = 0; half < 2; ++half) {
    if (half) __syncthreads();          // prev half's conv2 reads done

    // ---- zero pads for this half ----
    {
      u32x4* H = (u32x4*)h1s;
      u32x4 z = {0u,0u,0u,0u};
      const int zrow = half ? 15 : 0;   // full zero row (y'=0 / y'=29)
      if (t < 128) H[zrow*128 + t] = z;
      const int r0 = half ? 0 : 1;      // col pads on the 15 computed rows
      if (t < 240) {                    // 15 rows x 4 px x 4 chunks
        int rr = t >> 4, rem = t & 15;
        int pi = rem >> 2, sub = rem & 3;
        int px = pi == 0 ? 0 : 28 + pi; // x' in {0,29,30,31}
        H[((r0 + rr)*32 + px)*4 + sub] = z;
      }
    }

    // ---- conv1 via MFMA: A=k1[cout][tap], B=im2col[tap][pixel] ----
    const int ybase = half ? 13 : 0;
    for (int tid = wid; tid < 30; tid += 4) {
      const int ty = tid >> 1;                 // 0..14
      const int x0 = (tid & 1) << 4;
      const int yo = ybase + ty;               // conv output row
      const float* bp = &xs[yo*36 + x0 + l15];
      u32x4 bw;
      bw[0] = cvtpk(bp[off[0]], bp[off[1]]);
      bw[1] = cvtpk(bp[off[2]], bp[off[3]]);
      bw[2] = cvtpk(bp[off[4]], bp[off[5]]);
      bw[3] = cvtpk(bp[off[6]], bp[off[7]]);
      const bf16x8 bfrag = __builtin_bit_cast(bf16x8, bw);
      f32x4 d0 = {0.f,0.f,0.f,0.f}, d1 = {0.f,0.f,0.f,0.f};
      d0 = __builtin_amdgcn_mfma_f32_16x16x32_bf16(k1a0, bfrag, d0, 0, 0, 0);
      d1 = __builtin_amdgcn_mfma_f32_16x16x32_bf16(k1a1, bfrag, d1, 0, 0, 0);
      // D: col=l15=pixel, row=lk*4+reg=cout -> 4 consecutive couts per lane
      const int xo = x0 + l15;
      if (xo < 28) {
        const int ry = half ? (yo - 13) : (yo + 1);
        const int pix = ry*32 + xo + 1;
        const int swz = (pix >> 1) & 3;
        const int blkbase = (lk >> 1);
        unsigned int w0lo = cvtpk(fmaxf(d0[0] + b1v[0][0], 0.f), fmaxf(d0[1] + b1v[0][1], 0.f));
        unsigned int w0hi = cvtpk(fmaxf(d0[2] + b1v[0][2], 0.f), fmaxf(d0[3] + b1v[0][3], 0.f));
        unsigned int w1lo = cvtpk(fmaxf(d1[0] + b1v[1][0], 0.f), fmaxf(d1[1] + b1v[1][1], 0.f));
        unsigned int w1hi = cvtpk(fmaxf(d1[2] + b1v[1][2], 0.f), fmaxf(d1[3] + b1v[1][3], 0.f));
        char* base = (char*)h1s + pix*64 + (lk & 1)*8;
        *(u32x2*)(base + ((blkbase ^ swz) << 4))       = (u32x2){w0lo, w0hi};
        *(u32x2*)(base + (((2 + blkbase) ^ swz) << 4)) = (u32x2){w1lo, w1hi};
      }
    }
    __syncthreads();

    // ---- conv2 via MFMA ----
    const char* h1c = (const char*)h1s;
    for (int pyl = 0; pyl < 7; ++pyl) {
      const int py = half*7 + pyl;
      const int rbase = (2*py - (half ? 14 : 0)) * 2048;
      f32x4 acc[2][2];
      #pragma unroll
      for (int yi = 0; yi < 2; ++yi)
        #pragma unroll
        for (int nn = 0; nn < 2; ++nn) acc[yi][nn] = (f32x4){0.f,0.f,0.f,0.f};
      #pragma unroll
      for (int kx = 0; kx < 3; ++kx) {
        bf16x8 af[4];
        #pragma unroll
        for (int r = 0; r < 4; ++r)
          af[r] = *(const bf16x8*)(h1c + rbase + r*2048 + colOff[kx]);
        #pragma unroll
        for (int ky = 0; ky < 3; ++ky)
          #pragma unroll
          for (int yi = 0; yi < 2; ++yi) {
            acc[yi][0] = __builtin_amdgcn_mfma_f32_16x16x32_bf16(af[yi+ky], bfr[0][ky*3+kx], acc[yi][0], 0, 0, 0);
            acc[yi][1] = __builtin_amdgcn_mfma_f32_16x16x32_bf16(af[yi+ky], bfr[1][ky*3+kx], acc[yi][1], 0, 0, 0);
          }
      }
      // bias + relu + 2x2 maxpool in-register, write bf16
      float hm[2][2][2];   // [nn][yi][xpair]
      #pragma unroll
      for (int yi = 0; yi < 2; ++yi)
        #pragma unroll
        for (int nn = 0; nn < 2; ++nn) {
          float v0 = fmaxf(acc[yi][nn][0] + b2v[nn], 0.f);
          float v1 = fmaxf(acc[yi][nn][1] + b2v[nn], 0.f);
          float v2 = fmaxf(acc[yi][nn][2] + b2v[nn], 0.f);
          float v3 = fmaxf(acc[yi][nn][3] + b2v[nn], 0.f);
          hm[nn][yi][0] = fmaxf(v0, v1);
          hm[nn][yi][1] = fmaxf(v2, v3);
        }
      if (!(tx == 1 && lk == 3)) {                 // drop x>=28 dummy columns
        const int px0 = tx*8 + lk*2;
        #pragma unroll
        for (int nn = 0; nn < 2; ++nn) {
          float q0 = fmaxf(hm[nn][0][0], hm[nn][1][0]);
          float q1 = fmaxf(hm[nn][0][1], hm[nn][1][1]);
          const int c = ntp*32 + nn*16 + l15;
          *(unsigned int*)&h3[((size_t)(bimg*64 + c)*14 + py)*14 + px0] = cvtpk(q0, q1);
        }
      }
    }
  }
}

// ---------------- FC1 GEMM: M=2048 N=128 K=12544, kh=8, A staged in LDS ----------------
// As swizzled in 16B blocks: row r, block b stored at slot b ^ (r&7) (b<192; tail linear)
__global__ __launch_bounds__(256) void k_fc1(const unsigned short* __restrict__ h3,
                                             const unsigned short* __restrict__ fc1wb,
                                             float* __restrict__ h4p) {
  __shared__ __align__(16) unsigned short As[16 * FC1_KC];   // 50176 B
  const int bid = blockIdx.x;            // 128 mtiles x 8 kh
  const int mtile = bid >> 3, kh = bid & 7;
  const int t = threadIdx.x, lane = t & 63, w = t >> 6;
  const unsigned short* Ag = h3 + (size_t)(mtile*16)*12544 + kh*FC1_KC;

  // stage A: 3 x 1KB async direct-to-LDS per row (source pre-swizzled) + 64B tail
  #pragma unroll
  for (int rr = 0; rr < 4; ++rr) {
    const int r = w*4 + rr;
    const int f = r & 7;
    const unsigned short* rowg = Ag + (size_t)r*12544 + ((lane ^ f) * 8);
    #pragma unroll
    for (int p = 0; p < 3; ++p) {
      __builtin_amdgcn_global_load_lds(
          (const __attribute__((address_space(1))) unsigned int*)(rowg + p*512),
          (__attribute__((address_space(3))) unsigned int*)&As[r*FC1_KC + p*512],
          16, 0, 0);
    }
  }
  {
    const int r = t >> 4, o = (t & 15) * 2;
    *(unsigned int*)&As[r*FC1_KC + 1536 + o] =
        *(const unsigned int*)(Ag + (size_t)r*12544 + 1536 + o);
  }
  __syncthreads();

  const int l15 = lane & 15, lk = lane >> 4;
  const int swz = l15 & 7;
  const unsigned short* b0p = fc1wb + (size_t)(w*32 + l15)*12544 + kh*FC1_KC + lk*8;
  const unsigned short* b1p = b0p + (size_t)16*12544;

  f32x4 acc0 = {0.f,0.f,0.f,0.f}, acc1 = {0.f,0.f,0.f,0.f};
  #pragma unroll 7
  for (int ks = 0; ks < 49; ++ks) {
    const int b = ks*4 + lk;
    const int s = (ks < 48) ? (b ^ swz) : b;
    bf16x8 a  = *(const bf16x8*)&As[l15*FC1_KC + s*8];
    bf16x8 w0 = *(const bf16x8*)(b0p + ks*32);
    bf16x8 w1 = *(const bf16x8*)(b1p + ks*32);
    acc0 = __builtin_amdgcn_mfma_f32_16x16x32_bf16(a, w0, acc0, 0, 0, 0);
    acc1 = __builtin_amdgcn_mfma_f32_16x16x32_bf16(a, w1, acc1, 0, 0, 0);
  }
  float* outp = h4p + (size_t)kh * NB * 128;
  const int n0 = w*32 + l15;
  #pragma unroll
  for (int jj = 0; jj < 4; ++jj) {
    const int bb = mtile*16 + lk*4 + jj;
    outp[bb*128 + n0]      = acc0[jj];
    outp[bb*128 + n0 + 16] = acc1[jj];
  }
}

// ---------------- K-partial reduce + bias + relu + FC2 ----------------
__global__ __launch_bounds__(256) void k_fc2(const float* __restrict__ h4p,
                                             const float* __restrict__ fc1b,
                                             const float* __restrict__ fc2w,
                                             const float* __restrict__ fc2b,
                                             float* __restrict__ out) {
  __shared__ float hs[32*129];
  const int blk = blockIdx.x;    // 64 blocks x 32 batches
  const int t = threadIdx.x;
  for (int i = t; i < 4096; i += 256) {
    const int base = blk*4096 + i;
    float v = 0.f;
    #pragma unroll
    for (int kh = 0; kh < 8; ++kh) v += h4p[base + kh*262144];
    v += fc1b[i & 127];
    hs[(i >> 7)*129 + (i & 127)] = fmaxf(v, 0.f);
  }
  __syncthreads();
  for (int i = t; i < 320; i += 256) {
    const int bb = i / 10, n = i % 10;
    float acc = fc2b[n];
    const float* wr = fc2w + n*128;
    const float* hr = hs + bb*129;
    #pragma unroll 8
    for (int k = 0; k < 128; ++k) acc = fmaf(hr[k], wr[k], acc);
    out[(blk*32 + bb)*10 + n] = acc;
  }
}

extern "C" void kernel_launch(void* const* d_in, const int* in_sizes, int n_in,
                              void* d_out, int out_size, void* d_ws, size_t ws_size,
                              hipStream_t stream) {
  const float* x    = (const float*)d_in[0];
  const float* w1   = (const float*)d_in[1];
  const float* p1   = (const float*)d_in[2];
  const float* p2   = (const float*)d_in[3];
  const float* b1   = (const float*)d_in[4];
  const float* w2   = (const float*)d_in[5];
  const float* b2   = (const float*)d_in[6];
  const float* fc1w = (const float*)d_in[7];
  const float* fc1b = (const float*)d_in[8];
  const float* fc2w = (const float*)d_in[9];
  const float* fc2b = (const float*)d_in[10];

  // ws layout (bytes):
  //        0: k1b bf16[32][32]           (2048)
  //     4096: w2b bf16[9][64][32]        (36864)
  //    40960: fc1wb bf16[128][12544]     (3211264)
  //  3252224: h3 bf16[2048][64][14][14]  (51380224)
  // 54632448: h4p f32[8][2048][128]      (8388608)  -> total 63021056
  if (ws_size < 63021056u) return;
  char* ws = (char*)d_ws;
  unsigned short* k1b  = (unsigned short*)(ws + 0);
  unsigned short* w2b  = (unsigned short*)(ws + 4096);
  unsigned short* fc1wb= (unsigned short*)(ws + 40960);
  unsigned short* h3   = (unsigned short*)(ws + 3252224);
  float* h4p           = (float*)(ws + 54632448);

  k_prep<<<2048, 256, 0, stream>>>(w2, fc1w, w1, p1, p2, w2b, fc1wb, k1b);
  k_conv<<<NB, 256, 0, stream>>>(x, k1b, b1, w2b, b2, h3);
  k_fc1<<<1024, 256, 0, stream>>>(h3, fc1wb, h4p);
  k_fc2<<<64, 256, 0, stream>>>(h4p, fc1b, fc2w, fc2b, (float*)d_out);
}